// Round 8
// baseline (667.856 us; speedup 1.0000x reference)
//
#include <hip/hip_runtime.h>
#include <cstdint>

typedef float fx4 __attribute__((ext_vector_type(4)));
typedef short sx8 __attribute__((ext_vector_type(8)));

#define NSTATE 16
#define SEQ_LEN 2048
#define NBATCH 32
#define MROWS 65536           // NBATCH*SEQ_LEN
#define KDIM 1024
#define N1 1072               // z(1024) + B(16) + C(16) + delta(16)
#define N1PAD 1152            // 9 tiles of 128
#define BM 128
#define BN 128
#define BK 32
#define NSTEP (KDIM / BK)     // 32
#define RING 3
#define SLOT_SHORTS 4096      // 128x32 bf16 = 8KB per matrix per slot
#define TILE_SHORTS 4096      // packed tile = [128][32] shorts

__device__ __forceinline__ short f2bf(float f) {
  unsigned u = __float_as_uint(f);
  u += 0x7FFFu + ((u >> 16) & 1u);   // round-to-nearest-even
  return (short)(u >> 16);
}

// A&S 7.1.26 erf, |eps|<=1.5e-7, branchless. gelu(x)=0.5x(1+erf(x/sqrt2))
__device__ __forceinline__ float gelu_exact(float x) {
  float ax = fabsf(x) * 0.70710678118654752f;
  float t = __builtin_amdgcn_rcpf(fmaf(0.3275911f, ax, 1.0f));
  float p = fmaf(1.061405429f, t, -1.453152027f);
  p = fmaf(p, t, 1.421413741f);
  p = fmaf(p, t, -0.284496736f);
  p = fmaf(p, t, 0.254829592f);
  p = p * t;
  float e = __expf(-ax * ax);
  float erfv = fmaf(-p, e, 1.0f);
  erfv = copysignf(erfv, x);
  return 0.5f * x * (1.0f + erfv);
}

// default-policy staging (B: keep L2-resident)
#define GLOAD_LDS16(gp, lp)                                                          \
  __builtin_amdgcn_global_load_lds(                                                  \
      (const __attribute__((address_space(1))) unsigned int*)(gp),                   \
      (__attribute__((address_space(3))) unsigned int*)(lp), 16, 0, 0)
// non-temporal staging (A streams: don't pollute L2)
#define GLOAD_LDS16_NT(gp, lp)                                                       \
  __builtin_amdgcn_global_load_lds(                                                  \
      (const __attribute__((address_space(1))) unsigned int*)(gp),                   \
      (__attribute__((address_space(3))) unsigned int*)(lp), 16, 0, 2)

#define SBAR() __builtin_amdgcn_s_barrier()

// ------- convert x fp32 -> bf16, tile-packed [mt][kt][128][32] with slot rotation -------
// physical slot p of row r holds logical k-slot q=(p-(r>>1))&3  (same image the LDS wants)
__global__ void convert_pack_x(const float* __restrict__ x, short* __restrict__ xbp) {
  const int bid = blockIdx.x;            // 2048 blocks
  const int mt = bid >> 2, ktq = bid & 3;
  const int t = threadIdx.x;             // 256 threads
  const int h = t >> 7, r = t & 127;
  const int m = mt * 128 + r;
  const int rs = (r >> 1) & 3;
  for (int k2 = 0; k2 < 8; k2 += 2) {
    int kt = ktq * 8 + k2 + h;
    const fx4* px = (const fx4*)(x + (long)m * KDIM + kt * 32);
    short* dst = xbp + ((long)mt * NSTEP + kt) * TILE_SHORTS + r * 32;
#pragma unroll
    for (int q = 0; q < 4; q++) {        // logical 8-element group q
      fx4 va = px[q * 2], vb = px[q * 2 + 1];
      sx8 o;
      o[0] = f2bf(va[0]); o[1] = f2bf(va[1]); o[2] = f2bf(va[2]); o[3] = f2bf(va[3]);
      o[4] = f2bf(vb[0]); o[5] = f2bf(vb[1]); o[6] = f2bf(vb[2]); o[7] = f2bf(vb[3]);
      *(sx8*)(dst + ((q + rs) & 3) * 8) = o;
    }
  }
}

// ------- transpose weights -> packed [nt][kt][128][32] bf16 (zero-pad rows), rotated -------
__global__ void transpose_w_kernel(const float* __restrict__ src, short* __restrict__ dst,
                                   int src_cols, int col_off, int valid_rows) {
  __shared__ float t[32][33];
  int j0 = blockIdx.x * 32;
  int k0 = blockIdx.y * 32;
  int c = threadIdx.x & 31;
  int r = threadIdx.x >> 5;  // 0..7
#pragma unroll
  for (int i = 0; i < 4; i++) {
    int k = k0 + r + i * 8;
    int j = j0 + c;
    float v = (j < valid_rows) ? src[(long)k * src_cols + col_off + j] : 0.f;
    t[r + i * 8][c] = v;
  }
  __syncthreads();
#pragma unroll
  for (int i = 0; i < 4; i++) {
    int n = j0 + r + i * 8;
    int k = k0 + c;
    int rr = n & 127;
    long addr = ((long)(n >> 7) * NSTEP + (k >> 5)) * TILE_SHORTS + rr * 32
              + ((((k >> 3) & 3) + ((rr >> 1) & 3)) & 3) * 8 + (k & 7);
    dst[addr] = f2bf(t[c][r + i * 8]);
  }
}

// ---- 128x128 mainloop: ring-3 LDS, packed linear staging (src offset == LDS offset) ----
__device__ __forceinline__ void gemm_mainloop(const short* __restrict__ Abase,
                                              const short* __restrict__ Bbase,
                                              short* AshR, short* BshR,
                                              fx4 acc[4][4]) {
  const int tid = threadIdx.x;
  const int lane = tid & 63;
  const int wave = tid >> 6;
  const int wm = wave >> 1, wn = wave & 1;
  const int ks = lane >> 4;

#pragma unroll
  for (int i = 0; i < 4; i++)
#pragma unroll
    for (int j = 0; j < 4; j++) acc[i][j] = fx4{0.f, 0.f, 0.f, 0.f};

  const int d0 = (wave * 64 + lane) * 8;     // linear 16B-chunk offsets
  const int d1 = d0 + 2048;

  // fragment read offsets (rotation pre-applied in the packed image)
  int aof[4], bof[4];
#pragma unroll
  for (int i = 0; i < 4; i++) {
    int rr = wm * 64 + i * 16 + (lane & 15);
    aof[i] = rr * 32 + ((ks + ((rr >> 1) & 3)) & 3) * 8;
  }
#pragma unroll
  for (int j = 0; j < 4; j++) {
    int rn = wn * 64 + j * 16 + (lane & 15);
    bof[j] = rn * 32 + ((ks + ((rn >> 1) & 3)) & 3) * 8;
  }

  // prologue: stage steps 0,1,2 into slots 0,1,2
#pragma unroll
  for (int s = 0; s < RING; s++) {
    const short* ta = Abase + (long)s * TILE_SHORTS;
    const short* tb = Bbase + (long)s * TILE_SHORTS;
    short* sa = AshR + s * SLOT_SHORTS;
    short* sb = BshR + s * SLOT_SHORTS;
    GLOAD_LDS16_NT(ta + d0, sa + d0);
    GLOAD_LDS16_NT(ta + d1, sa + d1);
    GLOAD_LDS16(tb + d0, sb + d0);
    GLOAD_LDS16(tb + d1, sb + d1);
  }

  int slot = 0;
  for (int s = 0; s < NSTEP; ++s) {
    if (s <= NSTEP - 3)      asm volatile("s_waitcnt vmcnt(8)" ::: "memory");
    else if (s == NSTEP - 2) asm volatile("s_waitcnt vmcnt(4)" ::: "memory");
    else                     asm volatile("s_waitcnt vmcnt(0)" ::: "memory");
    SBAR();

    const short* sa = AshR + slot * SLOT_SHORTS;
    const short* sb = BshR + slot * SLOT_SHORTS;
    sx8 af[4], bfr[4];
#pragma unroll
    for (int i = 0; i < 4; i++) af[i] = *(const sx8*)(sa + aof[i]);
#pragma unroll
    for (int j = 0; j < 4; j++) bfr[j] = *(const sx8*)(sb + bof[j]);
    asm volatile("s_waitcnt lgkmcnt(0)" ::: "memory");
    __builtin_amdgcn_sched_barrier(0);

    __builtin_amdgcn_s_setprio(1);
#pragma unroll
    for (int i = 0; i < 4; i++)
#pragma unroll
      for (int j = 0; j < 4; j++)
        acc[i][j] = __builtin_amdgcn_mfma_f32_16x16x32_bf16(af[i], bfr[j], acc[i][j], 0, 0, 0);
    __builtin_amdgcn_s_setprio(0);

    SBAR();                                  // all waves done reading this slot
    if (s + RING < NSTEP) {                  // overwrite this slot with step s+3
      const short* ta = Abase + (long)(s + RING) * TILE_SHORTS;
      const short* tb = Bbase + (long)(s + RING) * TILE_SHORTS;
      short* wa = AshR + slot * SLOT_SHORTS;
      short* wb = BshR + slot * SLOT_SHORTS;
      GLOAD_LDS16_NT(ta + d0, wa + d0);
      GLOAD_LDS16_NT(ta + d1, wa + d1);
      GLOAD_LDS16(tb + d0, wb + d0);
      GLOAD_LDS16(tb + d1, wb + d1);
    }
    slot = (slot == RING - 1) ? 0 : slot + 1;
  }
}

// ---------------- GEMM1: xz = x @ W_in[:,1024:] + b_in[1024:], fused epilogue ---------------
__global__ __launch_bounds__(256, 3) void gemm1_kernel(
    const short* __restrict__ xbp, const short* __restrict__ Wt1p,
    const float* __restrict__ b_in, const float* __restrict__ A_log,
    short* __restrict__ g, float* __restrict__ Bb, float* __restrict__ Cb,
    float* __restrict__ ab) {
  __shared__ short Ash[RING * SLOT_SHORTS] __attribute__((aligned(16)));
  __shared__ short Bsh[RING * SLOT_SHORTS] __attribute__((aligned(16)));
  const int bid = blockIdx.x;                 // 0..4607
  const int wgid = (bid & 7) * 576 + (bid >> 3);
  const int nt = wgid % 9;
  const int mt = wgid / 9;
  fx4 acc[4][4];
  gemm_mainloop(xbp + (long)mt * NSTEP * TILE_SHORTS,
                Wt1p + (long)nt * NSTEP * TILE_SHORTS, Ash, Bsh, acc);

  const int lane = threadIdx.x & 63;
  const int wave = threadIdx.x >> 6;
  const int wm = wave >> 1, wn = wave & 1;
  const int n0 = nt * BN;
  const int m0 = mt * BM;

#pragma unroll
  for (int j = 0; j < 4; j++) {
    int n = n0 + wn * 64 + j * 16 + (lane & 15);
    if (n >= N1) continue;
    float bias = b_in[1024 + n];
#pragma unroll
    for (int i = 0; i < 4; i++) {
#pragma unroll
      for (int r = 0; r < 4; r++) {
        int m = m0 + wm * 64 + i * 16 + (lane >> 4) * 4 + r;
        float v = acc[i][j][r] + bias;
        if (n < 1024) {
          // write g TILE-PACKED (gemm2's A): [mt][n>>5][m&127][rotated slot]
          int rr = m & 127;
          long addr = ((long)(m >> 7) * NSTEP + (n >> 5)) * TILE_SHORTS + rr * 32
                    + ((((n >> 3) & 3) + ((rr >> 1) & 3)) & 3) * 8 + (n & 7);
          g[addr] = f2bf(gelu_exact(v));
        } else if (n < 1040) {
          Bb[m * NSTATE + (n - 1024)] = v;
        } else if (n < 1056) {
          Cb[m * NSTATE + (n - 1040)] = v;
        } else {
          int c = n - 1056;
          float dlt = (v > 20.f) ? v : log1pf(expf(v));
          float Ac = -expf(A_log[c]);
          ab[m * NSTATE + c] = expf(Ac * dlt);
        }
      }
    }
  }
}

// ---- selective scan: serial chain is fma-only; products written per-channel ----
__global__ void scan_kernel(const float* __restrict__ ab, const float* __restrict__ Bb,
                            const float* __restrict__ Cb, float* __restrict__ p) {
  int b = blockIdx.x;
  int ln = threadIdx.x;
  if (ln >= NSTATE) return;
  const float* pa = ab + b * SEQ_LEN * NSTATE + ln;
  const float* pb = Bb + b * SEQ_LEN * NSTATE + ln;
  const float* pc = Cb + b * SEQ_LEN * NSTATE + ln;
  float* po = p + (long)b * SEQ_LEN * NSTATE + ln;
  float s = 0.f;
  float a0[8], b0[8], c0[8], a1[8], b1[8], c1[8];
#pragma unroll
  for (int u = 0; u < 8; u++) {
    int o = u * NSTATE;
    a0[u] = pa[o]; b0[u] = pb[o]; c0[u] = pc[o];
  }
  for (int t0 = 0; t0 < SEQ_LEN; t0 += 16) {
#pragma unroll
    for (int u = 0; u < 8; u++) {
      int o = (t0 + 8 + u) * NSTATE;
      a1[u] = pa[o]; b1[u] = pb[o]; c1[u] = pc[o];
    }
#pragma unroll
    for (int u = 0; u < 8; u++) {
      s = fmaf(a0[u], s, b0[u]);
      po[(t0 + u) * NSTATE] = s * c0[u];
    }
    if (t0 + 16 < SEQ_LEN) {
#pragma unroll
      for (int u = 0; u < 8; u++) {
        int o = (t0 + 16 + u) * NSTATE;
        a0[u] = pa[o]; b0[u] = pb[o]; c0[u] = pc[o];
      }
    }
#pragma unroll
    for (int u = 0; u < 8; u++) {
      s = fmaf(a1[u], s, b1[u]);
      po[(t0 + 8 + u) * NSTATE] = s * c1[u];
    }
  }
}

// ---------------- reduce p over 16 channels -> y ----------------
__global__ void reduce_y_kernel(const float* __restrict__ p, float* __restrict__ y) {
  int m = blockIdx.x * blockDim.x + threadIdx.x;
  const fx4* row = (const fx4*)(p + (long)m * NSTATE);
  fx4 v = row[0] + row[1] + row[2] + row[3];
  y[m] = v[0] + v[1] + v[2] + v[3];
}

// ---------------- GEMM2: out = (y ⊙row g) @ W_out + b_out ----------------
__global__ __launch_bounds__(256, 3) void gemm2_kernel(
    const short* __restrict__ g, const short* __restrict__ Wt2p,
    const float* __restrict__ y, const float* __restrict__ b_out,
    float* __restrict__ out) {
  __shared__ short Ash[RING * SLOT_SHORTS] __attribute__((aligned(16)));
  __shared__ short Bsh[RING * SLOT_SHORTS] __attribute__((aligned(16)));
  const int bid = blockIdx.x;                 // 0..4095
  const int wgid = (bid & 7) * 512 + (bid >> 3);
  const int nt = wgid & 7;
  const int mt = wgid >> 3;
  fx4 acc[4][4];
  gemm_mainloop(g + (long)mt * NSTEP * TILE_SHORTS,
                Wt2p + (long)nt * NSTEP * TILE_SHORTS, Ash, Bsh, acc);

  const int lane = threadIdx.x & 63;
  const int wave = threadIdx.x >> 6;
  const int wm = wave >> 1, wn = wave & 1;
  const int m0 = mt * BM;
  const int n0 = nt * BN;

#pragma unroll
  for (int i = 0; i < 4; i++) {
#pragma unroll
    for (int r = 0; r < 4; r++) {
      int m = m0 + wm * 64 + i * 16 + (lane >> 4) * 4 + r;
      float ym = y[m];
#pragma unroll
      for (int j = 0; j < 4; j++) {
        int n = n0 + wn * 64 + j * 16 + (lane & 15);
        out[(long)m * 1024 + n] = fmaf(ym, acc[i][j][r], b_out[n]);
      }
    }
  }
}

extern "C" void kernel_launch(void* const* d_in, const int* in_sizes, int n_in,
                              void* d_out, int out_size, void* d_ws, size_t ws_size,
                              hipStream_t stream) {
  const float* x     = (const float*)d_in[0];
  const float* W_in  = (const float*)d_in[1];
  const float* b_in  = (const float*)d_in[2];
  const float* A_log = (const float*)d_in[3];
  const float* W_out = (const float*)d_in[4];
  const float* b_out = (const float*)d_in[5];
  float* out = (float*)d_out;

  char* ws = (char*)d_ws;
  short* xbp = (short*)ws;  ws += (size_t)MROWS * KDIM * 2;      // 134.2 MB packed
  short* g   = (short*)ws;  ws += (size_t)MROWS * KDIM * 2;      // 134.2 MB packed
  short* Wt1p = (short*)ws; ws += (size_t)N1PAD * KDIM * 2;      // 2.36 MB packed
  short* Wt2p = (short*)ws; ws += (size_t)KDIM * KDIM * 2;       // 2.10 MB packed
  float* Bb = (float*)ws;  ws += (size_t)MROWS * NSTATE * 4;     // 4.19 MB
  float* Cb = (float*)ws;  ws += (size_t)MROWS * NSTATE * 4;
  float* ab = (float*)ws;  ws += (size_t)MROWS * NSTATE * 4;
  float* p  = (float*)ws;  ws += (size_t)MROWS * NSTATE * 4;
  float* y  = (float*)ws;  ws += (size_t)MROWS * 4;

  convert_pack_x<<<2048, 256, 0, stream>>>(x, xbp);
  transpose_w_kernel<<<dim3(N1PAD / 32, 32), 256, 0, stream>>>(W_in, Wt1p, 2096, 1024, N1);
  transpose_w_kernel<<<dim3(32, 32), 256, 0, stream>>>(W_out, Wt2p, 1024, 0, 1024);
  gemm1_kernel<<<MROWS / BM * (N1PAD / BN), 256, 0, stream>>>(xbp, Wt1p, b_in, A_log, g, Bb, Cb, ab);
  scan_kernel<<<NBATCH, 64, 0, stream>>>(ab, Bb, Cb, p);
  reduce_y_kernel<<<MROWS / 256, 256, 0, stream>>>(p, y);
  gemm2_kernel<<<MROWS / BM * (KDIM / BN), 256, 0, stream>>>(g, Wt2p, y, b_out, out);
}

// Round 9
// 598.769 us; speedup vs baseline: 1.1154x; 1.1154x over previous
//
#include <hip/hip_runtime.h>
#include <cstdint>

typedef float fx4 __attribute__((ext_vector_type(4)));
typedef short sx8 __attribute__((ext_vector_type(8)));

#define NSTATE 16
#define SEQ_LEN 2048
#define NBATCH 32
#define MROWS 65536           // NBATCH*SEQ_LEN
#define KDIM 1024
#define N1 1072               // z(1024) + B(16) + C(16) + delta(16)
#define N1PAD 1280            // 10 packed 128-tiles = 5 super-tiles of 256
#define BK 32
#define NSTEP (KDIM / BK)     // 32
#define RING 4
#define TILE_SHORTS 4096      // packed 128x32 bf16 tile
#define SLOT_SHORTS 8192      // 256x32 = 2 packed tiles per matrix per ring slot

__device__ __forceinline__ short f2bf(float f) {
  unsigned u = __float_as_uint(f);
  u += 0x7FFFu + ((u >> 16) & 1u);   // round-to-nearest-even
  return (short)(u >> 16);
}

// A&S 7.1.26 erf, |eps|<=1.5e-7, branchless. gelu(x)=0.5x(1+erf(x/sqrt2))
__device__ __forceinline__ float gelu_exact(float x) {
  float ax = fabsf(x) * 0.70710678118654752f;
  float t = __builtin_amdgcn_rcpf(fmaf(0.3275911f, ax, 1.0f));
  float p = fmaf(1.061405429f, t, -1.453152027f);
  p = fmaf(p, t, 1.421413741f);
  p = fmaf(p, t, -0.284496736f);
  p = fmaf(p, t, 0.254829592f);
  p = p * t;
  float e = __expf(-ax * ax);
  float erfv = fmaf(-p, e, 1.0f);
  erfv = copysignf(erfv, x);
  return 0.5f * x * (1.0f + erfv);
}

#define GLOAD_LDS16(gp, lp)                                                          \
  __builtin_amdgcn_global_load_lds(                                                  \
      (const __attribute__((address_space(1))) unsigned int*)(gp),                   \
      (__attribute__((address_space(3))) unsigned int*)(lp), 16, 0, 0)

#define SBAR() __builtin_amdgcn_s_barrier()

// ------- convert x fp32 -> bf16, tile-packed [mt][kt][128][32] with slot rotation -------
// physical slot p of row r holds logical k-slot q=(p-(r>>1))&3
__global__ void convert_pack_x(const float* __restrict__ x, short* __restrict__ xbp) {
  const int bid = blockIdx.x;            // 2048 blocks
  const int mt = bid >> 2, ktq = bid & 3;
  const int t = threadIdx.x;             // 256 threads
  const int h = t >> 7, r = t & 127;
  const int m = mt * 128 + r;
  const int rs = (r >> 1) & 3;
  for (int k2 = 0; k2 < 8; k2 += 2) {
    int kt = ktq * 8 + k2 + h;
    const fx4* px = (const fx4*)(x + (long)m * KDIM + kt * 32);
    short* dst = xbp + ((long)mt * NSTEP + kt) * TILE_SHORTS + r * 32;
#pragma unroll
    for (int q = 0; q < 4; q++) {        // logical 8-element group q
      fx4 va = px[q * 2], vb = px[q * 2 + 1];
      sx8 o;
      o[0] = f2bf(va[0]); o[1] = f2bf(va[1]); o[2] = f2bf(va[2]); o[3] = f2bf(va[3]);
      o[4] = f2bf(vb[0]); o[5] = f2bf(vb[1]); o[6] = f2bf(vb[2]); o[7] = f2bf(vb[3]);
      *(sx8*)(dst + ((q + rs) & 3) * 8) = o;
    }
  }
}

// ------- transpose weights -> packed [nt][kt][128][32] bf16 (zero-pad rows), rotated -------
__global__ void transpose_w_kernel(const float* __restrict__ src, short* __restrict__ dst,
                                   int src_cols, int col_off, int valid_rows) {
  __shared__ float t[32][33];
  int j0 = blockIdx.x * 32;
  int k0 = blockIdx.y * 32;
  int c = threadIdx.x & 31;
  int r = threadIdx.x >> 5;  // 0..7
#pragma unroll
  for (int i = 0; i < 4; i++) {
    int k = k0 + r + i * 8;
    int j = j0 + c;
    float v = (j < valid_rows) ? src[(long)k * src_cols + col_off + j] : 0.f;
    t[r + i * 8][c] = v;
  }
  __syncthreads();
#pragma unroll
  for (int i = 0; i < 4; i++) {
    int n = j0 + r + i * 8;
    int k = k0 + c;
    int rr = n & 127;
    long addr = ((long)(n >> 7) * NSTEP + (k >> 5)) * TILE_SHORTS + rr * 32
              + ((((k >> 3) & 3) + ((rr >> 1) & 3)) & 3) * 8 + (k & 7);
    dst[addr] = f2bf(t[c][r + i * 8]);
  }
}

// ---- 256x256 mainloop: 1024 thr / 16 waves, ring-4 LDS, packed linear staging ----
// Abase/Bbase point at 2 consecutive packed 128-tiles (stride NSTEP*TILE_SHORTS).
__device__ __forceinline__ void gemm_mainloop256(const short* __restrict__ Abase,
                                                 const short* __restrict__ Bbase,
                                                 short* lds, fx4 acc[4][4]) {
  const int tid = threadIdx.x;
  const int lane = tid & 63;
  const int wave = tid >> 6;                 // 0..15
  const int wm = wave >> 2, wn = wave & 3;   // 4x4 wave grid; wave output 64x64
  const int ks = lane >> 4;

#pragma unroll
  for (int i = 0; i < 4; i++)
#pragma unroll
    for (int j = 0; j < 4; j++) acc[i][j] = fx4{0.f, 0.f, 0.f, 0.f};

  short* AshR = lds;                          // RING * 8192 shorts
  short* BshR = lds + RING * SLOT_SHORTS;

  // staging: thread t covers half h=t>>9, chunk c=t&511 (16B); LDS offset == t*8
  const short* Asrc = Abase + (long)(tid >> 9) * (NSTEP * TILE_SHORTS) + (tid & 511) * 8;
  const short* Bsrc = Bbase + (long)(tid >> 9) * (NSTEP * TILE_SHORTS) + (tid & 511) * 8;
  const int dst = tid * 8;

  // fragment bases. rotation key: rr&127 = (wm&1)*64 + i*16 + (lane&15);
  // ((rr&127)>>1)&3 == ((lane&15)>>1)&3 (64>>1=32≡0, 16>>1=8≡0 mod 4) -> lane-only.
  const int rslot = (ks + (((lane & 15) >> 1) & 3)) & 3;
  const int aoff = (wm >> 1) * TILE_SHORTS + ((wm & 1) * 64 + (lane & 15)) * 32 + rslot * 8;
  const int boff = (wn >> 1) * TILE_SHORTS + ((wn & 1) * 64 + (lane & 15)) * 32 + rslot * 8;

  // prologue: stage steps 0..3 into slots 0..3 (2 loads per thread per step)
#pragma unroll
  for (int s = 0; s < RING; s++) {
    GLOAD_LDS16(Asrc + (long)s * TILE_SHORTS, AshR + s * SLOT_SHORTS + dst);
    GLOAD_LDS16(Bsrc + (long)s * TILE_SHORTS, BshR + s * SLOT_SHORTS + dst);
  }

  int slot = 0;
  for (int s = 0; s < NSTEP; ++s) {
    // allow newest min(3, 31-s) stage-groups (2 loads each) to remain in flight
    if (s <= NSTEP - 4)      asm volatile("s_waitcnt vmcnt(6)" ::: "memory");
    else if (s == NSTEP - 3) asm volatile("s_waitcnt vmcnt(4)" ::: "memory");
    else if (s == NSTEP - 2) asm volatile("s_waitcnt vmcnt(2)" ::: "memory");
    else                     asm volatile("s_waitcnt vmcnt(0)" ::: "memory");
    SBAR();                                   // slot data visible to all waves

    const short* sa = AshR + slot * SLOT_SHORTS + aoff;
    const short* sb = BshR + slot * SLOT_SHORTS + boff;
    sx8 af[4], bfr[4];
#pragma unroll
    for (int i = 0; i < 4; i++) af[i] = *(const sx8*)(sa + i * 512);
#pragma unroll
    for (int j = 0; j < 4; j++) bfr[j] = *(const sx8*)(sb + j * 512);
    asm volatile("s_waitcnt lgkmcnt(0)" ::: "memory");
    __builtin_amdgcn_sched_barrier(0);

    __builtin_amdgcn_s_setprio(1);
#pragma unroll
    for (int i = 0; i < 4; i++)
#pragma unroll
      for (int j = 0; j < 4; j++)
        acc[i][j] = __builtin_amdgcn_mfma_f32_16x16x32_bf16(af[i], bfr[j], acc[i][j], 0, 0, 0);
    __builtin_amdgcn_s_setprio(0);

    SBAR();                                   // all waves done reading this slot
    if (s + RING < NSTEP) {                   // overwrite slot with step s+RING
      GLOAD_LDS16(Asrc + (long)(s + RING) * TILE_SHORTS, AshR + slot * SLOT_SHORTS + dst);
      GLOAD_LDS16(Bsrc + (long)(s + RING) * TILE_SHORTS, BshR + slot * SLOT_SHORTS + dst);
    }
    slot = (slot == RING - 1) ? 0 : slot + 1;
  }
}

// ---------------- GEMM1: xz = x @ W_in[:,1024:] + b_in[1024:], fused epilogue ---------------
__global__ __launch_bounds__(1024, 1) void gemm1_kernel(
    const short* __restrict__ xbp, const short* __restrict__ Wt1p,
    const float* __restrict__ b_in, const float* __restrict__ A_log,
    short* __restrict__ g, float* __restrict__ Bb, float* __restrict__ Cb,
    float* __restrict__ ab) {
  extern __shared__ short lds[];
  const int bid = blockIdx.x;                 // 0..1279
  const int wgid = (bid & 7) * 160 + (bid >> 3);
  const int nt = wgid % 5;
  const int mt = wgid / 5;                    // 0..255
  fx4 acc[4][4];
  gemm_mainloop256(xbp + (long)(mt * 2) * NSTEP * TILE_SHORTS,
                   Wt1p + (long)(nt * 2) * NSTEP * TILE_SHORTS, lds, acc);

  const int lane = threadIdx.x & 63;
  const int wave = threadIdx.x >> 6;
  const int wm = wave >> 2, wn = wave & 3;
  const int m0 = mt * 256;
  const int n0 = nt * 256;

#pragma unroll
  for (int j = 0; j < 4; j++) {
    int n = n0 + wn * 64 + j * 16 + (lane & 15);
    if (n >= N1) continue;
    float bias = b_in[1024 + n];
#pragma unroll
    for (int i = 0; i < 4; i++) {
#pragma unroll
      for (int r = 0; r < 4; r++) {
        int m = m0 + wm * 64 + i * 16 + (lane >> 4) * 4 + r;
        float v = acc[i][j][r] + bias;
        if (n < 1024) {
          // write g TILE-PACKED (gemm2's A): [m>>7][n>>5][m&127][rotated slot]
          int rr = m & 127;
          long addr = ((long)(m >> 7) * NSTEP + (n >> 5)) * TILE_SHORTS + rr * 32
                    + ((((n >> 3) & 3) + ((rr >> 1) & 3)) & 3) * 8 + (n & 7);
          g[addr] = f2bf(gelu_exact(v));
        } else if (n < 1040) {
          Bb[m * NSTATE + (n - 1024)] = v;
        } else if (n < 1056) {
          Cb[m * NSTATE + (n - 1040)] = v;
        } else {
          int c = n - 1056;
          float dlt = (v > 20.f) ? v : log1pf(expf(v));
          float Ac = -expf(A_log[c]);
          ab[m * NSTATE + c] = expf(Ac * dlt);
        }
      }
    }
  }
}

// ---- selective scan: serial chain is fma-only; products written per-channel ----
__global__ void scan_kernel(const float* __restrict__ ab, const float* __restrict__ Bb,
                            const float* __restrict__ Cb, float* __restrict__ p) {
  int b = blockIdx.x;
  int ln = threadIdx.x;
  if (ln >= NSTATE) return;
  const float* pa = ab + b * SEQ_LEN * NSTATE + ln;
  const float* pb = Bb + b * SEQ_LEN * NSTATE + ln;
  const float* pc = Cb + b * SEQ_LEN * NSTATE + ln;
  float* po = p + (long)b * SEQ_LEN * NSTATE + ln;
  float s = 0.f;
  float a0[8], b0[8], c0[8], a1[8], b1[8], c1[8];
#pragma unroll
  for (int u = 0; u < 8; u++) {
    int o = u * NSTATE;
    a0[u] = pa[o]; b0[u] = pb[o]; c0[u] = pc[o];
  }
  for (int t0 = 0; t0 < SEQ_LEN; t0 += 16) {
#pragma unroll
    for (int u = 0; u < 8; u++) {
      int o = (t0 + 8 + u) * NSTATE;
      a1[u] = pa[o]; b1[u] = pb[o]; c1[u] = pc[o];
    }
#pragma unroll
    for (int u = 0; u < 8; u++) {
      s = fmaf(a0[u], s, b0[u]);
      po[(t0 + u) * NSTATE] = s * c0[u];
    }
    if (t0 + 16 < SEQ_LEN) {
#pragma unroll
      for (int u = 0; u < 8; u++) {
        int o = (t0 + 16 + u) * NSTATE;
        a0[u] = pa[o]; b0[u] = pb[o]; c0[u] = pc[o];
      }
    }
#pragma unroll
    for (int u = 0; u < 8; u++) {
      s = fmaf(a1[u], s, b1[u]);
      po[(t0 + 8 + u) * NSTATE] = s * c1[u];
    }
  }
}

// ---------------- reduce p over 16 channels -> y ----------------
__global__ void reduce_y_kernel(const float* __restrict__ p, float* __restrict__ y) {
  int m = blockIdx.x * blockDim.x + threadIdx.x;
  const fx4* row = (const fx4*)(p + (long)m * NSTATE);
  fx4 v = row[0] + row[1] + row[2] + row[3];
  y[m] = v[0] + v[1] + v[2] + v[3];
}

// ---------------- GEMM2: out = (y ⊙row g) @ W_out + b_out ----------------
__global__ __launch_bounds__(1024, 1) void gemm2_kernel(
    const short* __restrict__ g, const short* __restrict__ Wt2p,
    const float* __restrict__ y, const float* __restrict__ b_out,
    float* __restrict__ out) {
  extern __shared__ short lds[];
  const int bid = blockIdx.x;                 // 0..1023
  const int wgid = (bid & 7) * 128 + (bid >> 3);
  const int nt = wgid & 3;
  const int mt = wgid >> 2;                   // 0..255
  fx4 acc[4][4];
  gemm_mainloop256(g + (long)(mt * 2) * NSTEP * TILE_SHORTS,
                   Wt2p + (long)(nt * 2) * NSTEP * TILE_SHORTS, lds, acc);

  const int lane = threadIdx.x & 63;
  const int wave = threadIdx.x >> 6;
  const int wm = wave >> 2, wn = wave & 3;
  const int m0 = mt * 256;
  const int n0 = nt * 256;

#pragma unroll
  for (int i = 0; i < 4; i++) {
#pragma unroll
    for (int r = 0; r < 4; r++) {
      int m = m0 + wm * 64 + i * 16 + (lane >> 4) * 4 + r;
      float ym = y[m];
#pragma unroll
      for (int j = 0; j < 4; j++) {
        int n = n0 + wn * 64 + j * 16 + (lane & 15);
        out[(long)m * 1024 + n] = fmaf(ym, acc[i][j][r], b_out[n]);
      }
    }
  }
}

extern "C" void kernel_launch(void* const* d_in, const int* in_sizes, int n_in,
                              void* d_out, int out_size, void* d_ws, size_t ws_size,
                              hipStream_t stream) {
  const float* x     = (const float*)d_in[0];
  const float* W_in  = (const float*)d_in[1];
  const float* b_in  = (const float*)d_in[2];
  const float* A_log = (const float*)d_in[3];
  const float* W_out = (const float*)d_in[4];
  const float* b_out = (const float*)d_in[5];
  float* out = (float*)d_out;

  char* ws = (char*)d_ws;
  short* xbp = (short*)ws;  ws += (size_t)MROWS * KDIM * 2;      // 134.2 MB packed
  short* g   = (short*)ws;  ws += (size_t)MROWS * KDIM * 2;      // 134.2 MB packed
  short* Wt1p = (short*)ws; ws += (size_t)N1PAD * KDIM * 2;      // 2.6 MB packed
  short* Wt2p = (short*)ws; ws += (size_t)KDIM * KDIM * 2;       // 2.1 MB packed
  float* Bb = (float*)ws;  ws += (size_t)MROWS * NSTATE * 4;     // 4.19 MB
  float* Cb = (float*)ws;  ws += (size_t)MROWS * NSTATE * 4;
  float* ab = (float*)ws;  ws += (size_t)MROWS * NSTATE * 4;
  float* p  = (float*)ws;  ws += (size_t)MROWS * NSTATE * 4;
  float* y  = (float*)ws;  ws += (size_t)MROWS * 4;

  const int ldsBytes = 2 * RING * SLOT_SHORTS * 2;   // 128 KB

  convert_pack_x<<<2048, 256, 0, stream>>>(x, xbp);
  transpose_w_kernel<<<dim3(N1PAD / 32, 32), 256, 0, stream>>>(W_in, Wt1p, 2096, 1024, N1);
  transpose_w_kernel<<<dim3(32, 32), 256, 0, stream>>>(W_out, Wt2p, 1024, 0, 1024);
  gemm1_kernel<<<(MROWS / 256) * (N1PAD / 256), 1024, ldsBytes, stream>>>(
      xbp, Wt1p, b_in, A_log, g, Bb, Cb, ab);
  scan_kernel<<<NBATCH, 64, 0, stream>>>(ab, Bb, Cb, p);
  reduce_y_kernel<<<MROWS / 256, 256, 0, stream>>>(p, y);
  gemm2_kernel<<<(MROWS / 256) * (KDIM / 256), 1024, ldsBytes, stream>>>(
      g, Wt2p, y, b_out, out);
}